// Round 2
// baseline (2202.414 us; speedup 1.0000x reference)
//
#include <hip/hip_runtime.h>
#include <math.h>
#include <stdint.h>

#define S_LEN 1024
#define D_DIM 64
#define BH    32
#define NBINS 1040384u            // 0x3F800000 >> 10 : |score| < 1.0
#define NCHUNK 254                // NBINS / 4096
#define INV_NM1 (1.0f/33554431.0f)
#define INV_N   (2.9802322387695312e-08f)  // 1/2^25

// ---------------- row norms in fp64: 1/(||row||+1e-5) ----------------
__global__ __launch_bounds__(256) void norms_kernel(
    const float* __restrict__ Q, const float* __restrict__ K,
    double* __restrict__ qinv, double* __restrict__ kinv) {
  int row  = blockIdx.x * 4 + (threadIdx.x >> 6);
  int lane = threadIdx.x & 63;
  const float* src; double* dst; int r = row;
  if (row < BH * S_LEN) { src = Q; dst = qinv; }
  else                  { src = K; dst = kinv; r = row - BH * S_LEN; }
  double v = (double)src[(size_t)r * D_DIM + lane];
  double s = v * v;
  #pragma unroll
  for (int off = 32; off; off >>= 1) s += __shfl_down(s, off);
  if (lane == 0) dst[r] = 1.0 / (sqrt(s) + 1e-5);
}

// ---------------- QK^T (fp64 accumulate, normalized) + histogram ----------------
__global__ __launch_bounds__(256) void qk_kernel(
    const float* __restrict__ Q, const float* __restrict__ K,
    const double* __restrict__ qinv, const double* __restrict__ kinv,
    float* __restrict__ score, unsigned* __restrict__ hist) {
  __shared__ float Qs[64][68];   // [k][i]
  __shared__ float Ks[64][68];   // [k][j]
  int bh = blockIdx.z;
  int i0 = blockIdx.y * 64;
  int j0 = blockIdx.x * 64;
  int tid = threadIdx.x;
  const float* Qb = Q + ((size_t)bh * S_LEN + i0) * D_DIM;
  const float* Kb = K + ((size_t)bh * S_LEN + j0) * D_DIM;
  #pragma unroll
  for (int l = 0; l < 4; ++l) {
    int idx4 = l * 256 + tid;
    int row  = idx4 >> 4;
    int c4   = idx4 & 15;
    float4 v = ((const float4*)Qb)[row * 16 + c4];
    Qs[c4*4+0][row] = v.x; Qs[c4*4+1][row] = v.y;
    Qs[c4*4+2][row] = v.z; Qs[c4*4+3][row] = v.w;
    float4 w = ((const float4*)Kb)[row * 16 + c4];
    Ks[c4*4+0][row] = w.x; Ks[c4*4+1][row] = w.y;
    Ks[c4*4+2][row] = w.z; Ks[c4*4+3][row] = w.w;
  }
  __syncthreads();
  int tx = tid & 15, ty = tid >> 4;
  double acc[4][4] = {{0}};
  #pragma unroll 4
  for (int k = 0; k < 64; ++k) {
    float4 a = *(const float4*)&Qs[k][ty*4];
    float4 b = *(const float4*)&Ks[k][tx*4];
    double ad[4] = {(double)a.x, (double)a.y, (double)a.z, (double)a.w};
    double bd[4] = {(double)b.x, (double)b.y, (double)b.z, (double)b.w};
    #pragma unroll
    for (int r = 0; r < 4; ++r)
      #pragma unroll
      for (int c = 0; c < 4; ++c)
        acc[r][c] = fma(ad[r], bd[c], acc[r][c]);
  }
  double qi[4], kj[4];
  #pragma unroll
  for (int r = 0; r < 4; ++r) qi[r] = qinv[(size_t)bh * S_LEN + i0 + ty*4 + r];
  #pragma unroll
  for (int c = 0; c < 4; ++c) kj[c] = kinv[(size_t)bh * S_LEN + j0 + tx*4 + c];
  #pragma unroll
  for (int r = 0; r < 4; ++r) {
    float4 st;
    float* sp = (float*)&st;
    #pragma unroll
    for (int c = 0; c < 4; ++c) {
      float s = (float)(acc[r][c] * qi[r] * kj[c]);
      sp[c] = s;
      unsigned key = __float_as_uint(fabsf(s));
      unsigned b = key >> 10;
      if (b >= NBINS) b = NBINS - 1u;
      atomicAdd(&hist[b], 1u);
    }
    *(float4*)(score + ((size_t)bh * S_LEN + i0 + ty*4 + r) * S_LEN + j0 + tx*4) = st;
  }
}

// ---------------- histogram exclusive scan (3 stages) ----------------
__global__ __launch_bounds__(256) void scan1_kernel(const unsigned* __restrict__ hist,
                                                    unsigned* __restrict__ csum) {
  __shared__ unsigned sd[256];
  int c = blockIdx.x, t = threadIdx.x;
  const unsigned* p = hist + (size_t)c * 4096;
  unsigned s = 0;
  #pragma unroll
  for (int l = 0; l < 16; ++l) s += p[t + l * 256];
  sd[t] = s; __syncthreads();
  for (int off = 128; off; off >>= 1) {
    if (t < off) sd[t] += sd[t + off];
    __syncthreads();
  }
  if (t == 0) csum[c] = sd[0];
}

__global__ __launch_bounds__(256) void scan2_kernel(unsigned* __restrict__ csum) {
  __shared__ unsigned d[256];
  int t = threadIdx.x;
  unsigned v = (t < NCHUNK) ? csum[t] : 0u;
  d[t] = v; __syncthreads();
  for (int off = 1; off < 256; off <<= 1) {
    unsigned x = (t >= off) ? d[t - off] : 0u;
    __syncthreads();
    d[t] += x;
    __syncthreads();
  }
  if (t < NCHUNK) csum[t] = d[t] - v;   // exclusive
}

__global__ __launch_bounds__(256) void scan3_kernel(const unsigned* __restrict__ hist,
                                                    const unsigned* __restrict__ csum,
                                                    unsigned* __restrict__ excl) {
  __shared__ unsigned ts[256];
  int c = blockIdx.x, t = threadIdx.x;
  const unsigned* p = hist + (size_t)c * 4096 + t * 16;
  unsigned loc[16]; unsigned s = 0;
  #pragma unroll
  for (int l = 0; l < 16; ++l) { loc[l] = p[l]; s += loc[l]; }
  ts[t] = s; __syncthreads();
  for (int off = 1; off < 256; off <<= 1) {
    unsigned x = (t >= off) ? ts[t - off] : 0u;
    __syncthreads();
    ts[t] += x;
    __syncthreads();
  }
  unsigned base = csum[c] + (t ? ts[t - 1] : 0u);
  unsigned* q = excl + (size_t)c * 4096 + t * 16;
  #pragma unroll
  for (int l = 0; l < 16; ++l) { q[l] = base; base += loc[l]; }
}

// ---------------- fused map(-log rank * sign) + rowsum + P·V ----------------
__global__ __launch_bounds__(256) void pv_kernel(
    const float* __restrict__ score, const float* __restrict__ V,
    const unsigned* __restrict__ hist, const unsigned* __restrict__ excl,
    float* __restrict__ out) {
  __shared__ float tS[16][64];
  __shared__ float Vs[64][64];
  __shared__ float rs[16][17];
  __shared__ float rsInv[16];
  int bh = blockIdx.y;
  int i0 = blockIdx.x * 16;
  int tid = threadIdx.x;
  int mr  = tid >> 4;
  int mc4 = tid & 15;
  int td  = tid & 63;
  int tg  = tid >> 6;
  const float* Vb = V + (size_t)bh * S_LEN * D_DIM;
  const float* Sb = score + ((size_t)bh * S_LEN + i0) * S_LEN;
  float acc[4] = {0.f, 0.f, 0.f, 0.f};
  float rsum = 0.f;
  for (int ch = 0; ch < 16; ++ch) {
    int j0 = ch * 64;
    float4 vreg[4];
    #pragma unroll
    for (int l = 0; l < 4; ++l) {
      int idx4 = l * 256 + tid; int row = idx4 >> 4; int c4 = idx4 & 15;
      vreg[l] = *(const float4*)(Vb + (size_t)(j0 + row) * D_DIM + c4 * 4);
    }
    float4 sv = *(const float4*)(Sb + (size_t)mr * S_LEN + j0 + mc4 * 4);
    float tv[4];
    #pragma unroll
    for (int c = 0; c < 4; ++c) {
      float s = ((const float*)&sv)[c];
      unsigned key = __float_as_uint(fabsf(s));
      unsigned b = key >> 10;
      if (b >= NBINS) b = NBINS - 1u;
      float A   = (float)excl[b];
      float cnt = (float)hist[b];
      float rr  = A + 0.5f * (cnt - 1.0f);       // midpoint rank, exact when cnt==1
      float prob = fmaf(rr, INV_NM1, INV_N);
      float t = -__logf(prob);
      float o = (s > 0.f) ? t : ((s < 0.f) ? -t : 0.f);
      tv[c] = o;
      rsum += fabsf(o);
    }
    __syncthreads();
    #pragma unroll
    for (int l = 0; l < 4; ++l) {
      int idx4 = l * 256 + tid; int row = idx4 >> 4; int c4 = idx4 & 15;
      *(float4*)&Vs[row][c4 * 4] = vreg[l];
    }
    *(float4*)&tS[mr][mc4 * 4] = make_float4(tv[0], tv[1], tv[2], tv[3]);
    __syncthreads();
    #pragma unroll
    for (int jj4 = 0; jj4 < 16; ++jj4) {
      float4 t0 = *(const float4*)&tS[tg*4+0][jj4*4];
      float4 t1 = *(const float4*)&tS[tg*4+1][jj4*4];
      float4 t2 = *(const float4*)&tS[tg*4+2][jj4*4];
      float4 t3 = *(const float4*)&tS[tg*4+3][jj4*4];
      float v0 = Vs[jj4*4+0][td], v1 = Vs[jj4*4+1][td];
      float v2 = Vs[jj4*4+2][td], v3 = Vs[jj4*4+3][td];
      acc[0]=fmaf(t0.x,v0,acc[0]); acc[0]=fmaf(t0.y,v1,acc[0]); acc[0]=fmaf(t0.z,v2,acc[0]); acc[0]=fmaf(t0.w,v3,acc[0]);
      acc[1]=fmaf(t1.x,v0,acc[1]); acc[1]=fmaf(t1.y,v1,acc[1]); acc[1]=fmaf(t1.z,v2,acc[1]); acc[1]=fmaf(t1.w,v3,acc[1]);
      acc[2]=fmaf(t2.x,v0,acc[2]); acc[2]=fmaf(t2.y,v1,acc[2]); acc[2]=fmaf(t2.z,v2,acc[2]); acc[2]=fmaf(t2.w,v3,acc[2]);
      acc[3]=fmaf(t3.x,v0,acc[3]); acc[3]=fmaf(t3.y,v1,acc[3]); acc[3]=fmaf(t3.z,v2,acc[3]); acc[3]=fmaf(t3.w,v3,acc[3]);
    }
  }
  __syncthreads();
  rs[mr][mc4] = rsum;
  __syncthreads();
  if (tid < 16) {
    float s = 0.f;
    #pragma unroll
    for (int c = 0; c < 16; ++c) s += rs[tid][c];
    rsInv[tid] = 1.0f / s;
  }
  __syncthreads();
  #pragma unroll
  for (int r = 0; r < 4; ++r) {
    out[((size_t)bh * S_LEN + i0 + tg*4 + r) * D_DIM + td] = acc[r] * rsInv[tg*4 + r];
  }
}

// ---------------- launch ----------------
extern "C" void kernel_launch(void* const* d_in, const int* in_sizes, int n_in,
                              void* d_out, int out_size, void* d_ws, size_t ws_size,
                              hipStream_t stream) {
  const float* Q = (const float*)d_in[0];
  const float* K = (const float*)d_in[1];
  const float* V = (const float*)d_in[2];
  float* out = (float*)d_out;
  char* ws = (char*)d_ws;
  float*    score = (float*)(ws);                     // 134,217,728 B
  unsigned* hist  = (unsigned*)(ws + 134217728);      //   4,161,536 B
  unsigned* excl  = (unsigned*)(ws + 138379264);      //   4,161,536 B
  unsigned* csum  = (unsigned*)(ws + 142540800);      //       1,024 B
  double*   qinv  = (double*)(ws + 142541824);        //     262,144 B
  double*   kinv  = (double*)(ws + 142803968);        //     262,144 B

  hipMemsetAsync(hist, 0, NBINS * sizeof(unsigned), stream);
  norms_kernel<<<(2 * BH * S_LEN) / 4, 256, 0, stream>>>(Q, K, qinv, kinv);
  qk_kernel<<<dim3(16, 16, BH), 256, 0, stream>>>(Q, K, qinv, kinv, score, hist);
  scan1_kernel<<<NCHUNK, 256, 0, stream>>>(hist, csum);
  scan2_kernel<<<1, 256, 0, stream>>>(csum);
  scan3_kernel<<<NCHUNK, 256, 0, stream>>>(hist, csum, excl);
  pv_kernel<<<dim3(64, BH), 256, 0, stream>>>(score, V, hist, excl, out);
}

// Round 3
// 483.448 us; speedup vs baseline: 4.5556x; 4.5556x over previous
//
#include <hip/hip_runtime.h>
#include <math.h>
#include <stdint.h>

#define S_LEN 1024
#define D_DIM 64
#define BH    32
#define KSHIFT 13
#define NBINS 130048u             // 0x3F800000 >> 13 : |score| < 1.0, 18-bit keys
#define HOT_LO 115712u            // (113<<23)>>13 : |s| >= 2^-14
#define NHOT   14336u             // NBINS - HOT_LO
#define NCHUNK 254                // NBINS / 512
#define HBLK   128                // hist kernel blocks
#define INV_NM1 (1.0f/33554431.0f)
#define INV_N   (2.9802322387695312e-08f)  // 1/2^25

// ---------------- row norms in fp64: 1/(||row||+1e-5) ----------------
__global__ __launch_bounds__(256) void norms_kernel(
    const float* __restrict__ Q, const float* __restrict__ K,
    double* __restrict__ qinv, double* __restrict__ kinv) {
  int row  = blockIdx.x * 4 + (threadIdx.x >> 6);
  int lane = threadIdx.x & 63;
  const float* src; double* dst; int r = row;
  if (row < BH * S_LEN) { src = Q; dst = qinv; }
  else                  { src = K; dst = kinv; r = row - BH * S_LEN; }
  double v = (double)src[(size_t)r * D_DIM + lane];
  double s = v * v;
  #pragma unroll
  for (int off = 32; off; off >>= 1) s += __shfl_down(s, off);
  if (lane == 0) dst[r] = 1.0 / (sqrt(s) + 1e-5);
}

// ---------------- QK^T (fp64 accumulate, normalized) -> score ----------------
__global__ __launch_bounds__(256) void qk_kernel(
    const float* __restrict__ Q, const float* __restrict__ K,
    const double* __restrict__ qinv, const double* __restrict__ kinv,
    float* __restrict__ score) {
  __shared__ float Qs[64][68];   // [k][i]
  __shared__ float Ks[64][68];   // [k][j]
  int bh = blockIdx.z;
  int i0 = blockIdx.y * 64;
  int j0 = blockIdx.x * 64;
  int tid = threadIdx.x;
  const float* Qb = Q + ((size_t)bh * S_LEN + i0) * D_DIM;
  const float* Kb = K + ((size_t)bh * S_LEN + j0) * D_DIM;
  #pragma unroll
  for (int l = 0; l < 4; ++l) {
    int idx4 = l * 256 + tid;
    int row  = idx4 >> 4;
    int c4   = idx4 & 15;
    float4 v = ((const float4*)Qb)[row * 16 + c4];
    Qs[c4*4+0][row] = v.x; Qs[c4*4+1][row] = v.y;
    Qs[c4*4+2][row] = v.z; Qs[c4*4+3][row] = v.w;
    float4 w = ((const float4*)Kb)[row * 16 + c4];
    Ks[c4*4+0][row] = w.x; Ks[c4*4+1][row] = w.y;
    Ks[c4*4+2][row] = w.z; Ks[c4*4+3][row] = w.w;
  }
  __syncthreads();
  int tx = tid & 15, ty = tid >> 4;
  double acc[4][4] = {{0}};
  #pragma unroll 4
  for (int k = 0; k < 64; ++k) {
    float4 a = *(const float4*)&Qs[k][ty*4];
    float4 b = *(const float4*)&Ks[k][tx*4];
    double ad[4] = {(double)a.x, (double)a.y, (double)a.z, (double)a.w};
    double bd[4] = {(double)b.x, (double)b.y, (double)b.z, (double)b.w};
    #pragma unroll
    for (int r = 0; r < 4; ++r)
      #pragma unroll
      for (int c = 0; c < 4; ++c)
        acc[r][c] = fma(ad[r], bd[c], acc[r][c]);
  }
  double qi[4], kj[4];
  #pragma unroll
  for (int r = 0; r < 4; ++r) qi[r] = qinv[(size_t)bh * S_LEN + i0 + ty*4 + r];
  #pragma unroll
  for (int c = 0; c < 4; ++c) kj[c] = kinv[(size_t)bh * S_LEN + j0 + tx*4 + c];
  #pragma unroll
  for (int r = 0; r < 4; ++r) {
    float4 st;
    float* sp = (float*)&st;
    #pragma unroll
    for (int c = 0; c < 4; ++c) sp[c] = (float)(acc[r][c] * qi[r] * kj[c]);
    *(float4*)(score + ((size_t)bh * S_LEN + i0 + ty*4 + r) * S_LEN + j0 + tx*4) = st;
  }
}

// ---------------- histogram: LDS-privatized hot range + streamed flush ----------------
__global__ __launch_bounds__(512) void hist_kernel(
    const float* __restrict__ score, unsigned* __restrict__ hist,
    unsigned* __restrict__ partial) {
  __shared__ unsigned lh[NHOT];
  int tid = threadIdx.x;
  for (unsigned i = tid; i < NHOT; i += 512) lh[i] = 0u;
  __syncthreads();
  // 33.5M floats = 8,388,608 float4; 65536 float4 per block; 128 per thread
  const float4* p = (const float4*)score + (size_t)blockIdx.x * 65536;
  #pragma unroll 4
  for (int it = 0; it < 128; ++it) {
    float4 v = p[it * 512 + tid];
    float vv[4] = {v.x, v.y, v.z, v.w};
    #pragma unroll
    for (int c = 0; c < 4; ++c) {
      unsigned b = __float_as_uint(fabsf(vv[c])) >> KSHIFT;
      if (b >= NBINS) b = NBINS - 1u;
      if (b >= HOT_LO) atomicAdd(&lh[b - HOT_LO], 1u);
      else             atomicAdd(&hist[b], 1u);     // rare (~4e-4 of values)
    }
  }
  __syncthreads();
  unsigned* dst = partial + (size_t)blockIdx.x * NHOT;
  for (unsigned i = tid; i < NHOT; i += 512) dst[i] = lh[i];
}

// ---------------- reduce partial histograms into hist hot range ----------------
__global__ __launch_bounds__(256) void hreduce_kernel(
    const unsigned* __restrict__ partial, unsigned* __restrict__ hist) {
  unsigned bin = blockIdx.x * 256 + threadIdx.x;   // 56 blocks * 256 = 14336
  unsigned s = 0;
  #pragma unroll 8
  for (int b = 0; b < HBLK; ++b) s += partial[(size_t)b * NHOT + bin];
  hist[HOT_LO + bin] = s;   // hot bins written only here; cold bins only by atomics
}

// ---------------- histogram exclusive scan (3 stages), chunk=512 ----------------
__global__ __launch_bounds__(256) void scan1_kernel(const unsigned* __restrict__ hist,
                                                    unsigned* __restrict__ csum) {
  __shared__ unsigned sd[256];
  int c = blockIdx.x, t = threadIdx.x;
  const unsigned* p = hist + (size_t)c * 512;
  sd[t] = p[t] + p[t + 256];
  __syncthreads();
  for (int off = 128; off; off >>= 1) {
    if (t < off) sd[t] += sd[t + off];
    __syncthreads();
  }
  if (t == 0) csum[c] = sd[0];
}

__global__ __launch_bounds__(256) void scan2_kernel(unsigned* __restrict__ csum) {
  __shared__ unsigned d[256];
  int t = threadIdx.x;
  unsigned v = (t < NCHUNK) ? csum[t] : 0u;
  d[t] = v; __syncthreads();
  for (int off = 1; off < 256; off <<= 1) {
    unsigned x = (t >= off) ? d[t - off] : 0u;
    __syncthreads();
    d[t] += x;
    __syncthreads();
  }
  if (t < NCHUNK) csum[t] = d[t] - v;   // exclusive
}

__global__ __launch_bounds__(256) void scan3_kernel(const unsigned* __restrict__ hist,
                                                    const unsigned* __restrict__ csum,
                                                    uint2* __restrict__ cd) {
  __shared__ unsigned ts[256];
  int c = blockIdx.x, t = threadIdx.x;
  const unsigned* p = hist + (size_t)c * 512 + t * 2;
  unsigned l0 = p[0], l1 = p[1];
  unsigned s = l0 + l1;
  ts[t] = s; __syncthreads();
  for (int off = 1; off < 256; off <<= 1) {
    unsigned x = (t >= off) ? ts[t - off] : 0u;
    __syncthreads();
    ts[t] += x;
    __syncthreads();
  }
  unsigned base = csum[c] + ts[t] - s;
  uint2* q = cd + (size_t)c * 512 + t * 2;
  q[0] = make_uint2(base, l0);
  q[1] = make_uint2(base + l0, l1);
}

// ---------------- fused map(-log rank * sign) + rowsum + P·V ----------------
__global__ __launch_bounds__(256) void pv_kernel(
    const float* __restrict__ score, const float* __restrict__ V,
    const uint2* __restrict__ cd, float* __restrict__ out) {
  __shared__ float tS[16][64];
  __shared__ float Vs[64][64];
  __shared__ float rs[16][17];
  __shared__ float rsInv[16];
  int bh = blockIdx.y;
  int i0 = blockIdx.x * 16;
  int tid = threadIdx.x;
  int mr  = tid >> 4;
  int mc4 = tid & 15;
  int td  = tid & 63;
  int tg  = tid >> 6;
  const float* Vb = V + (size_t)bh * S_LEN * D_DIM;
  const float* Sb = score + ((size_t)bh * S_LEN + i0) * S_LEN;
  float acc[4] = {0.f, 0.f, 0.f, 0.f};
  float rsum = 0.f;
  for (int ch = 0; ch < 16; ++ch) {
    int j0 = ch * 64;
    float4 vreg[4];
    #pragma unroll
    for (int l = 0; l < 4; ++l) {
      int idx4 = l * 256 + tid; int row = idx4 >> 4; int c4 = idx4 & 15;
      vreg[l] = *(const float4*)(Vb + (size_t)(j0 + row) * D_DIM + c4 * 4);
    }
    float4 sv = *(const float4*)(Sb + (size_t)mr * S_LEN + j0 + mc4 * 4);
    float tv[4];
    #pragma unroll
    for (int c = 0; c < 4; ++c) {
      float s = ((const float*)&sv)[c];
      unsigned b = __float_as_uint(fabsf(s)) >> KSHIFT;
      if (b >= NBINS) b = NBINS - 1u;
      uint2 ec = cd[b];
      float A   = (float)ec.x;
      float cnt = (float)ec.y;
      float rr  = A + 0.5f * (cnt - 1.0f);       // midpoint rank, exact when cnt==1
      float prob = fmaf(rr, INV_NM1, INV_N);
      float t = -__logf(prob);
      float o = (s > 0.f) ? t : ((s < 0.f) ? -t : 0.f);
      tv[c] = o;
      rsum += fabsf(o);
    }
    __syncthreads();
    #pragma unroll
    for (int l = 0; l < 4; ++l) {
      int idx4 = l * 256 + tid; int row = idx4 >> 4; int c4 = idx4 & 15;
      *(float4*)&Vs[row][c4 * 4] = vreg[l];
    }
    *(float4*)&tS[mr][mc4 * 4] = make_float4(tv[0], tv[1], tv[2], tv[3]);
    __syncthreads();
    #pragma unroll
    for (int jj4 = 0; jj4 < 16; ++jj4) {
      float4 t0 = *(const float4*)&tS[tg*4+0][jj4*4];
      float4 t1 = *(const float4*)&tS[tg*4+1][jj4*4];
      float4 t2 = *(const float4*)&tS[tg*4+2][jj4*4];
      float4 t3 = *(const float4*)&tS[tg*4+3][jj4*4];
      float v0 = Vs[jj4*4+0][td], v1 = Vs[jj4*4+1][td];
      float v2 = Vs[jj4*4+2][td], v3 = Vs[jj4*4+3][td];
      acc[0]=fmaf(t0.x,v0,acc[0]); acc[0]=fmaf(t0.y,v1,acc[0]); acc[0]=fmaf(t0.z,v2,acc[0]); acc[0]=fmaf(t0.w,v3,acc[0]);
      acc[1]=fmaf(t1.x,v0,acc[1]); acc[1]=fmaf(t1.y,v1,acc[1]); acc[1]=fmaf(t1.z,v2,acc[1]); acc[1]=fmaf(t1.w,v3,acc[1]);
      acc[2]=fmaf(t2.x,v0,acc[2]); acc[2]=fmaf(t2.y,v1,acc[2]); acc[2]=fmaf(t2.z,v2,acc[2]); acc[2]=fmaf(t2.w,v3,acc[2]);
      acc[3]=fmaf(t3.x,v0,acc[3]); acc[3]=fmaf(t3.y,v1,acc[3]); acc[3]=fmaf(t3.z,v2,acc[3]); acc[3]=fmaf(t3.w,v3,acc[3]);
    }
  }
  __syncthreads();
  rs[mr][mc4] = rsum;
  __syncthreads();
  if (tid < 16) {
    float s = 0.f;
    #pragma unroll
    for (int c = 0; c < 16; ++c) s += rs[tid][c];
    rsInv[tid] = 1.0f / s;
  }
  __syncthreads();
  #pragma unroll
  for (int r = 0; r < 4; ++r) {
    out[((size_t)bh * S_LEN + i0 + tg*4 + r) * D_DIM + td] = acc[r] * rsInv[tg*4 + r];
  }
}

// ---------------- launch ----------------
extern "C" void kernel_launch(void* const* d_in, const int* in_sizes, int n_in,
                              void* d_out, int out_size, void* d_ws, size_t ws_size,
                              hipStream_t stream) {
  const float* Q = (const float*)d_in[0];
  const float* K = (const float*)d_in[1];
  const float* V = (const float*)d_in[2];
  float* out = (float*)d_out;
  char* ws = (char*)d_ws;
  // Layout (total <= 142.1 MB; round-2-proven ws >= 143.0 MB):
  //   score   [0, 134217728)
  //   hist    [134217728, 134737920)          130048 u32
  //   transient "partial" region [134737920, 142077952)  128*14336 u32
  //     aliased AFTER partial is dead / not yet live:
  //     csum  at 134737920 (written by scan1, after hreduce consumed partial)
  //     cd    at 134738944 (written by scan3)
  //     qinv  at 135779328, kinv at 136041472 (dead before hist_kernel runs)
  float*    score   = (float*)(ws);
  unsigned* hist    = (unsigned*)(ws + 134217728);
  unsigned* partial = (unsigned*)(ws + 134737920);
  unsigned* csum    = (unsigned*)(ws + 134737920);
  uint2*    cd      = (uint2*)   (ws + 134738944);
  double*   qinv    = (double*)  (ws + 135779328);
  double*   kinv    = (double*)  (ws + 136041472);

  hipMemsetAsync(hist, 0, NBINS * sizeof(unsigned), stream);
  norms_kernel<<<(2 * BH * S_LEN) / 4, 256, 0, stream>>>(Q, K, qinv, kinv);
  qk_kernel<<<dim3(16, 16, BH), 256, 0, stream>>>(Q, K, qinv, kinv, score);
  hist_kernel<<<HBLK, 512, 0, stream>>>(score, hist, partial);
  hreduce_kernel<<<NHOT / 256, 256, 0, stream>>>(partial, hist);
  scan1_kernel<<<NCHUNK, 256, 0, stream>>>(hist, csum);
  scan2_kernel<<<1, 256, 0, stream>>>(csum);
  scan3_kernel<<<NCHUNK, 256, 0, stream>>>(hist, csum, cd);
  pv_kernel<<<dim3(64, BH), 256, 0, stream>>>(score, V, cd, out);
}

// Round 4
// 371.259 us; speedup vs baseline: 5.9323x; 1.3022x over previous
//
#include <hip/hip_runtime.h>
#include <math.h>
#include <stdint.h>

#define S_LEN 1024
#define D_DIM 64
#define BH    32
#define KSHIFT 13
#define NBINS 130048u             // 0x3F800000 >> 13 : |score| < 1.0, 18-bit keys
#define HOT_LO 115712u            // (113<<23)>>13 : |s| >= 2^-14
#define NHOT   14336u             // NBINS - HOT_LO
#define NCHUNK 254                // NBINS / 512
#define HBLK   256                // hist kernel blocks
#define PAD_T  38                 // tT row stride (even -> b64 align; 4-way max write conflict)
#define INV_NM1 (1.0f/33554431.0f)
#define INV_N   (2.9802322387695312e-08f)  // 1/2^25

// ---------------- row norms in fp64: 1/(||row||+1e-5) ----------------
__global__ __launch_bounds__(256) void norms_kernel(
    const float* __restrict__ Q, const float* __restrict__ K,
    double* __restrict__ qinv, double* __restrict__ kinv) {
  int row  = blockIdx.x * 4 + (threadIdx.x >> 6);
  int lane = threadIdx.x & 63;
  const float* src; double* dst; int r = row;
  if (row < BH * S_LEN) { src = Q; dst = qinv; }
  else                  { src = K; dst = kinv; r = row - BH * S_LEN; }
  double v = (double)src[(size_t)r * D_DIM + lane];
  double s = v * v;
  #pragma unroll
  for (int off = 32; off; off >>= 1) s += __shfl_down(s, off);
  if (lane == 0) dst[r] = 1.0 / (sqrt(s) + 1e-5);
}

// ---------------- QK^T (fp64 accumulate, normalized) -> score ----------------
__global__ __launch_bounds__(256) void qk_kernel(
    const float* __restrict__ Q, const float* __restrict__ K,
    const double* __restrict__ qinv, const double* __restrict__ kinv,
    float* __restrict__ score) {
  __shared__ float Qs[64][68];   // [k][i]
  __shared__ float Ks[64][68];   // [k][j]
  int bh = blockIdx.z;
  int i0 = blockIdx.y * 64;
  int j0 = blockIdx.x * 64;
  int tid = threadIdx.x;
  const float* Qb = Q + ((size_t)bh * S_LEN + i0) * D_DIM;
  const float* Kb = K + ((size_t)bh * S_LEN + j0) * D_DIM;
  #pragma unroll
  for (int l = 0; l < 4; ++l) {
    int idx4 = l * 256 + tid;
    int row  = idx4 >> 4;
    int c4   = idx4 & 15;
    float4 v = ((const float4*)Qb)[row * 16 + c4];
    Qs[c4*4+0][row] = v.x; Qs[c4*4+1][row] = v.y;
    Qs[c4*4+2][row] = v.z; Qs[c4*4+3][row] = v.w;
    float4 w = ((const float4*)Kb)[row * 16 + c4];
    Ks[c4*4+0][row] = w.x; Ks[c4*4+1][row] = w.y;
    Ks[c4*4+2][row] = w.z; Ks[c4*4+3][row] = w.w;
  }
  __syncthreads();
  int tx = tid & 15, ty = tid >> 4;
  double acc[4][4] = {{0}};
  #pragma unroll 4
  for (int k = 0; k < 64; ++k) {
    float4 a = *(const float4*)&Qs[k][ty*4];
    float4 b = *(const float4*)&Ks[k][tx*4];
    double ad[4] = {(double)a.x, (double)a.y, (double)a.z, (double)a.w};
    double bd[4] = {(double)b.x, (double)b.y, (double)b.z, (double)b.w};
    #pragma unroll
    for (int r = 0; r < 4; ++r)
      #pragma unroll
      for (int c = 0; c < 4; ++c)
        acc[r][c] = fma(ad[r], bd[c], acc[r][c]);
  }
  double qi[4], kj[4];
  #pragma unroll
  for (int r = 0; r < 4; ++r) qi[r] = qinv[(size_t)bh * S_LEN + i0 + ty*4 + r];
  #pragma unroll
  for (int c = 0; c < 4; ++c) kj[c] = kinv[(size_t)bh * S_LEN + j0 + tx*4 + c];
  #pragma unroll
  for (int r = 0; r < 4; ++r) {
    float4 st;
    float* sp = (float*)&st;
    #pragma unroll
    for (int c = 0; c < 4; ++c) sp[c] = (float)(acc[r][c] * qi[r] * kj[c]);
    *(float4*)(score + ((size_t)bh * S_LEN + i0 + ty*4 + r) * S_LEN + j0 + tx*4) = st;
  }
}

// ---------------- histogram: LDS-privatized hot range + u16 partial flush ----------------
__global__ __launch_bounds__(512) void hist_kernel(
    const float* __restrict__ score, unsigned* __restrict__ hist,
    unsigned short* __restrict__ partial) {
  __shared__ unsigned lh[NHOT];
  int tid = threadIdx.x;
  for (unsigned i = tid; i < NHOT; i += 512) lh[i] = 0u;
  __syncthreads();
  // 33.5M floats = 8,388,608 float4; 32768 float4 per block; 64 per thread
  const float4* p = (const float4*)score + (size_t)blockIdx.x * 32768;
  #pragma unroll 4
  for (int it = 0; it < 64; ++it) {
    float4 v = p[it * 512 + tid];
    float vv[4] = {v.x, v.y, v.z, v.w};
    #pragma unroll
    for (int c = 0; c < 4; ++c) {
      unsigned b = __float_as_uint(fabsf(vv[c])) >> KSHIFT;
      if (b >= NBINS) b = NBINS - 1u;
      if (b >= HOT_LO) atomicAdd(&lh[b - HOT_LO], 1u);
      else             atomicAdd(&hist[b], 1u);     // rare (~4e-4 of values)
    }
  }
  __syncthreads();
  unsigned short* dst = partial + (size_t)blockIdx.x * NHOT;
  for (unsigned i = tid; i < NHOT; i += 512) dst[i] = (unsigned short)lh[i];
}

// ---------------- reduce partial histograms into hist hot range ----------------
__global__ __launch_bounds__(256) void hreduce_kernel(
    const unsigned short* __restrict__ partial, unsigned* __restrict__ hist) {
  unsigned bin = blockIdx.x * 256 + threadIdx.x;   // 56 blocks * 256 = 14336
  unsigned s = 0;
  #pragma unroll 8
  for (int b = 0; b < HBLK; ++b) s += (unsigned)partial[(size_t)b * NHOT + bin];
  hist[HOT_LO + bin] = s;   // hot bins written only here; cold bins only by atomics
}

// ---------------- histogram exclusive scan (3 stages), chunk=512 ----------------
__global__ __launch_bounds__(256) void scan1_kernel(const unsigned* __restrict__ hist,
                                                    unsigned* __restrict__ csum) {
  __shared__ unsigned sd[256];
  int c = blockIdx.x, t = threadIdx.x;
  const unsigned* p = hist + (size_t)c * 512;
  sd[t] = p[t] + p[t + 256];
  __syncthreads();
  for (int off = 128; off; off >>= 1) {
    if (t < off) sd[t] += sd[t + off];
    __syncthreads();
  }
  if (t == 0) csum[c] = sd[0];
}

__global__ __launch_bounds__(256) void scan2_kernel(unsigned* __restrict__ csum) {
  __shared__ unsigned d[256];
  int t = threadIdx.x;
  unsigned v = (t < NCHUNK) ? csum[t] : 0u;
  d[t] = v; __syncthreads();
  for (int off = 1; off < 256; off <<= 1) {
    unsigned x = (t >= off) ? d[t - off] : 0u;
    __syncthreads();
    d[t] += x;
    __syncthreads();
  }
  if (t < NCHUNK) csum[t] = d[t] - v;   // exclusive
}

// scan3: per-bin rank -> transformed magnitude table tTab[b] = -log(prob(midrank))
__global__ __launch_bounds__(256) void scan3_kernel(const unsigned* __restrict__ hist,
                                                    const unsigned* __restrict__ csum,
                                                    float* __restrict__ tTab) {
  __shared__ unsigned ts[256];
  int c = blockIdx.x, t = threadIdx.x;
  const unsigned* p = hist + (size_t)c * 512 + t * 2;
  unsigned l0 = p[0], l1 = p[1];
  unsigned s = l0 + l1;
  ts[t] = s; __syncthreads();
  for (int off = 1; off < 256; off <<= 1) {
    unsigned x = (t >= off) ? ts[t - off] : 0u;
    __syncthreads();
    ts[t] += x;
    __syncthreads();
  }
  unsigned base = csum[c] + ts[t] - s;
  int idx = c * 512 + t * 2;
  float r0 = (float)base + 0.5f * ((float)l0 - 1.0f);          // midpoint rank
  tTab[idx]     = -__logf(fmaf(r0, INV_NM1, INV_N));           // cnt==0 bins unused
  float r1 = (float)(base + l0) + 0.5f * ((float)l1 - 1.0f);
  tTab[idx + 1] = -__logf(fmaf(r1, INV_NM1, INV_N));
}

// ---------------- fused map + rowsum + P·V (2x4 register tile) ----------------
__global__ __launch_bounds__(256, 4) void pv_kernel(
    const float* __restrict__ score, const float* __restrict__ V,
    const float* __restrict__ tTab, float* __restrict__ out) {
  __shared__ float Vs[64][64];       // [j][d]
  __shared__ float tT[64][PAD_T];    // [j][row], row < 32
  __shared__ float rs[32][17];
  __shared__ float rsInv[32];
  int bh = blockIdx.y;
  int i0 = blockIdx.x * 32;
  int tid = threadIdx.x;
  int sr = tid >> 4;        // 0..15 : score-row (and +16)
  int sc = tid & 15;        // 0..15 : j-slice (4 consecutive j)
  const float* Vb = V + (size_t)bh * S_LEN * D_DIM;
  const float* Sb = score + ((size_t)bh * S_LEN + i0) * S_LEN;
  float acc[2][4] = {{0.f,0.f,0.f,0.f},{0.f,0.f,0.f,0.f}};
  float rAcc0 = 0.f, rAcc1 = 0.f;
  for (int ch = 0; ch < 16; ++ch) {
    int j0 = ch * 64;
    float4 vreg[4];
    #pragma unroll
    for (int l = 0; l < 4; ++l) {
      int idx4 = l * 256 + tid; int jr = idx4 >> 4; int d4 = idx4 & 15;
      vreg[l] = *(const float4*)(Vb + (size_t)(j0 + jr) * D_DIM + d4 * 4);
    }
    float4 s0 = *(const float4*)(Sb + (size_t)sr * S_LEN + j0 + sc * 4);
    float4 s1 = *(const float4*)(Sb + (size_t)(sr + 16) * S_LEN + j0 + sc * 4);
    float o0[4], o1[4];
    const float* s0p = (const float*)&s0;
    const float* s1p = (const float*)&s1;
    #pragma unroll
    for (int c = 0; c < 4; ++c) {
      float sa = s0p[c];
      unsigned b = __float_as_uint(fabsf(sa)) >> KSHIFT;
      if (b >= NBINS) b = NBINS - 1u;
      float t = tTab[b];
      float o = (sa > 0.f) ? t : ((sa < 0.f) ? -t : 0.f);
      o0[c] = o; rAcc0 += fabsf(o);
      float sb = s1p[c];
      unsigned b2 = __float_as_uint(fabsf(sb)) >> KSHIFT;
      if (b2 >= NBINS) b2 = NBINS - 1u;
      float t2 = tTab[b2];
      float o2 = (sb > 0.f) ? t2 : ((sb < 0.f) ? -t2 : 0.f);
      o1[c] = o2; rAcc1 += fabsf(o2);
    }
    __syncthreads();   // previous chunk's FMA reads done before overwrite
    #pragma unroll
    for (int l = 0; l < 4; ++l) {
      int idx4 = l * 256 + tid; int jr = idx4 >> 4; int d4 = idx4 & 15;
      *(float4*)&Vs[jr][d4 * 4] = vreg[l];
    }
    #pragma unroll
    for (int c = 0; c < 4; ++c) {
      tT[sc * 4 + c][sr]      = o0[c];
      tT[sc * 4 + c][sr + 16] = o1[c];
    }
    __syncthreads();
    // FMA: thread = (rp = tid>>4 rows rp*2..+1, cg = tid&15 cols cg*4..+3)
    #pragma unroll 16
    for (int j = 0; j < 64; ++j) {
      float2 t2v = *(const float2*)&tT[j][sr * 2];   // sr == rp
      float4 v4  = *(const float4*)&Vs[j][sc * 4];   // sc == cg
      acc[0][0] = fmaf(t2v.x, v4.x, acc[0][0]);
      acc[0][1] = fmaf(t2v.x, v4.y, acc[0][1]);
      acc[0][2] = fmaf(t2v.x, v4.z, acc[0][2]);
      acc[0][3] = fmaf(t2v.x, v4.w, acc[0][3]);
      acc[1][0] = fmaf(t2v.y, v4.x, acc[1][0]);
      acc[1][1] = fmaf(t2v.y, v4.y, acc[1][1]);
      acc[1][2] = fmaf(t2v.y, v4.z, acc[1][2]);
      acc[1][3] = fmaf(t2v.y, v4.w, acc[1][3]);
    }
  }
  __syncthreads();
  rs[sr][sc]      = rAcc0;
  rs[sr + 16][sc] = rAcc1;
  __syncthreads();
  if (tid < 32) {
    float s = 0.f;
    #pragma unroll
    for (int c = 0; c < 16; ++c) s += rs[tid][c];
    rsInv[tid] = 1.0f / s;
  }
  __syncthreads();
  #pragma unroll
  for (int r = 0; r < 2; ++r) {
    float inv = rsInv[sr * 2 + r];
    float4 o = make_float4(acc[r][0] * inv, acc[r][1] * inv,
                           acc[r][2] * inv, acc[r][3] * inv);
    *(float4*)(out + ((size_t)bh * S_LEN + i0 + sr * 2 + r) * D_DIM + sc * 4) = o;
  }
}

// ---------------- launch ----------------
extern "C" void kernel_launch(void* const* d_in, const int* in_sizes, int n_in,
                              void* d_out, int out_size, void* d_ws, size_t ws_size,
                              hipStream_t stream) {
  const float* Q = (const float*)d_in[0];
  const float* K = (const float*)d_in[1];
  const float* V = (const float*)d_in[2];
  float* out = (float*)d_out;
  char* ws = (char*)d_ws;
  // Layout (max 142,077,952 B; <= round-3-proven footprint):
  //   score   [0, 134217728)
  //   hist    [134217728, 134737920)               130048 u32
  //   partial [134737920, 142077952)  256*14336 u16 (transient)
  //   aliased into partial's range after/before its lifetime:
  //     csum  at 134737920 (1024 B, written after hreduce)
  //     tTab  at 134738944 (520192 B, written by scan3)
  //     qinv  at 135260160, kinv at 135522304 (dead before hist_kernel)
  float*          score   = (float*)(ws);
  unsigned*       hist    = (unsigned*)(ws + 134217728);
  unsigned short* partial = (unsigned short*)(ws + 134737920);
  unsigned*       csum    = (unsigned*)(ws + 134737920);
  float*          tTab    = (float*)(ws + 134738944);
  double*         qinv    = (double*)(ws + 135260160);
  double*         kinv    = (double*)(ws + 135522304);

  hipMemsetAsync(hist, 0, NBINS * sizeof(unsigned), stream);
  norms_kernel<<<(2 * BH * S_LEN) / 4, 256, 0, stream>>>(Q, K, qinv, kinv);
  qk_kernel<<<dim3(16, 16, BH), 256, 0, stream>>>(Q, K, qinv, kinv, score);
  hist_kernel<<<HBLK, 512, 0, stream>>>(score, hist, partial);
  hreduce_kernel<<<NHOT / 256, 256, 0, stream>>>(partial, hist);
  scan1_kernel<<<NCHUNK, 256, 0, stream>>>(hist, csum);
  scan2_kernel<<<1, 256, 0, stream>>>(csum);
  scan3_kernel<<<NCHUNK, 256, 0, stream>>>(hist, csum, tTab);
  pv_kernel<<<dim3(32, BH), 256, 0, stream>>>(score, V, tTab, out);
}

// Round 5
// 292.372 us; speedup vs baseline: 7.5329x; 1.2698x over previous
//
#include <hip/hip_runtime.h>
#include <math.h>
#include <stdint.h>

#define S_LEN 1024
#define D_DIM 64
#define BH    32
#define KSHIFT 13
#define NBINS 130048u             // 0x3F800000 >> 13 : |score| < 1.0, 18-bit keys
#define HOT_LO 115712u            // (113<<23)>>13 : |s| >= 2^-14
#define NHOT   14336u             // NBINS - HOT_LO
#define NCHUNK 254                // NBINS / 512
#define HBLK   256                // hist kernel blocks
#define INV_NM1 (1.0f/33554431.0f)
#define INV_N   (2.9802322387695312e-08f)  // 1/2^25

typedef _Float16 half8 __attribute__((ext_vector_type(8)));
typedef float    floatx4 __attribute__((ext_vector_type(4)));

// ---------------- row norms in fp64: 1/(||row||+1e-5) ----------------
__global__ __launch_bounds__(256) void norms_kernel(
    const float* __restrict__ Q, const float* __restrict__ K,
    double* __restrict__ qinv, double* __restrict__ kinv) {
  int row  = blockIdx.x * 4 + (threadIdx.x >> 6);
  int lane = threadIdx.x & 63;
  const float* src; double* dst; int r = row;
  if (row < BH * S_LEN) { src = Q; dst = qinv; }
  else                  { src = K; dst = kinv; r = row - BH * S_LEN; }
  double v = (double)src[(size_t)r * D_DIM + lane];
  double s = v * v;
  #pragma unroll
  for (int off = 32; off; off >>= 1) s += __shfl_down(s, off);
  if (lane == 0) dst[r] = 1.0 / (sqrt(s) + 1e-5);
}

// ---------------- QK^T (fp64 accumulate, normalized) -> score ----------------
__global__ __launch_bounds__(256) void qk_kernel(
    const float* __restrict__ Q, const float* __restrict__ K,
    const double* __restrict__ qinv, const double* __restrict__ kinv,
    float* __restrict__ score) {
  __shared__ float Qs[64][68];   // [k][i]
  __shared__ float Ks[64][68];   // [k][j]
  int bh = blockIdx.z;
  int i0 = blockIdx.y * 64;
  int j0 = blockIdx.x * 64;
  int tid = threadIdx.x;
  const float* Qb = Q + ((size_t)bh * S_LEN + i0) * D_DIM;
  const float* Kb = K + ((size_t)bh * S_LEN + j0) * D_DIM;
  #pragma unroll
  for (int l = 0; l < 4; ++l) {
    int idx4 = l * 256 + tid;
    int row  = idx4 >> 4;
    int c4   = idx4 & 15;
    float4 v = ((const float4*)Qb)[row * 16 + c4];
    Qs[c4*4+0][row] = v.x; Qs[c4*4+1][row] = v.y;
    Qs[c4*4+2][row] = v.z; Qs[c4*4+3][row] = v.w;
    float4 w = ((const float4*)Kb)[row * 16 + c4];
    Ks[c4*4+0][row] = w.x; Ks[c4*4+1][row] = w.y;
    Ks[c4*4+2][row] = w.z; Ks[c4*4+3][row] = w.w;
  }
  __syncthreads();
  int tx = tid & 15, ty = tid >> 4;
  double acc[4][4] = {{0}};
  #pragma unroll 4
  for (int k = 0; k < 64; ++k) {
    float4 a = *(const float4*)&Qs[k][ty*4];
    float4 b = *(const float4*)&Ks[k][tx*4];
    double ad[4] = {(double)a.x, (double)a.y, (double)a.z, (double)a.w};
    double bd[4] = {(double)b.x, (double)b.y, (double)b.z, (double)b.w};
    #pragma unroll
    for (int r = 0; r < 4; ++r)
      #pragma unroll
      for (int c = 0; c < 4; ++c)
        acc[r][c] = fma(ad[r], bd[c], acc[r][c]);
  }
  double qi[4], kj[4];
  #pragma unroll
  for (int r = 0; r < 4; ++r) qi[r] = qinv[(size_t)bh * S_LEN + i0 + ty*4 + r];
  #pragma unroll
  for (int c = 0; c < 4; ++c) kj[c] = kinv[(size_t)bh * S_LEN + j0 + tx*4 + c];
  #pragma unroll
  for (int r = 0; r < 4; ++r) {
    float4 st;
    float* sp = (float*)&st;
    #pragma unroll
    for (int c = 0; c < 4; ++c) sp[c] = (float)(acc[r][c] * qi[r] * kj[c]);
    *(float4*)(score + ((size_t)bh * S_LEN + i0 + ty*4 + r) * S_LEN + j0 + tx*4) = st;
  }
}

// ---------------- histogram: LDS-privatized hot range + u16 partial flush ----------------
__global__ __launch_bounds__(512) void hist_kernel(
    const float* __restrict__ score, unsigned* __restrict__ hist,
    unsigned short* __restrict__ partial) {
  __shared__ unsigned lh[NHOT];
  int tid = threadIdx.x;
  for (unsigned i = tid; i < NHOT; i += 512) lh[i] = 0u;
  __syncthreads();
  const float4* p = (const float4*)score + (size_t)blockIdx.x * 32768;
  #pragma unroll 4
  for (int it = 0; it < 64; ++it) {
    float4 v = p[it * 512 + tid];
    float vv[4] = {v.x, v.y, v.z, v.w};
    #pragma unroll
    for (int c = 0; c < 4; ++c) {
      unsigned b = __float_as_uint(fabsf(vv[c])) >> KSHIFT;
      if (b >= NBINS) b = NBINS - 1u;
      if (b >= HOT_LO) atomicAdd(&lh[b - HOT_LO], 1u);
      else             atomicAdd(&hist[b], 1u);     // rare (~4e-4 of values)
    }
  }
  __syncthreads();
  unsigned short* dst = partial + (size_t)blockIdx.x * NHOT;
  for (unsigned i = tid; i < NHOT; i += 512) dst[i] = (unsigned short)lh[i];
}

// ---------------- reduce partial histograms into hist hot range ----------------
__global__ __launch_bounds__(256) void hreduce_kernel(
    const unsigned short* __restrict__ partial, unsigned* __restrict__ hist) {
  unsigned bin = blockIdx.x * 256 + threadIdx.x;
  unsigned s = 0;
  #pragma unroll 8
  for (int b = 0; b < HBLK; ++b) s += (unsigned)partial[(size_t)b * NHOT + bin];
  hist[HOT_LO + bin] = s;
}

// ---------------- V (fp32 [j][d]) -> Vt (fp16 [d][j]) ----------------
__global__ __launch_bounds__(256) void vt_kernel(
    const float* __restrict__ V, _Float16* __restrict__ Vt) {
  __shared__ _Float16 T[64][72];
  int bh = blockIdx.y, j0 = blockIdx.x * 64, tid = threadIdx.x;
  const float* Vb = V + ((size_t)bh * S_LEN + j0) * D_DIM;
  #pragma unroll
  for (int l = 0; l < 4; ++l) {
    int idx = l * 256 + tid;          // 0..1023 float4 of the 64x64 tile
    int jr = idx >> 4, d4 = idx & 15;
    float4 v = ((const float4*)Vb)[idx];
    T[d4*4+0][jr] = (_Float16)v.x;
    T[d4*4+1][jr] = (_Float16)v.y;
    T[d4*4+2][jr] = (_Float16)v.z;
    T[d4*4+3][jr] = (_Float16)v.w;
  }
  __syncthreads();
  _Float16* Ob = Vt + (size_t)bh * D_DIM * S_LEN + j0;
  #pragma unroll
  for (int l = 0; l < 2; ++l) {
    int idx = l * 256 + tid;          // 0..511 : d(64) x jc(8)
    int d = idx >> 3, jc = idx & 7;
    uint4 val = *(const uint4*)&T[d][jc*8];
    *(uint4*)(Ob + (size_t)d * S_LEN + jc*8) = val;
  }
}

// ---------------- histogram exclusive scan (3 stages), chunk=512 ----------------
__global__ __launch_bounds__(256) void scan1_kernel(const unsigned* __restrict__ hist,
                                                    unsigned* __restrict__ csum) {
  __shared__ unsigned sd[256];
  int c = blockIdx.x, t = threadIdx.x;
  const unsigned* p = hist + (size_t)c * 512;
  sd[t] = p[t] + p[t + 256];
  __syncthreads();
  for (int off = 128; off; off >>= 1) {
    if (t < off) sd[t] += sd[t + off];
    __syncthreads();
  }
  if (t == 0) csum[c] = sd[0];
}

__global__ __launch_bounds__(256) void scan2_kernel(unsigned* __restrict__ csum) {
  __shared__ unsigned d[256];
  int t = threadIdx.x;
  unsigned v = (t < NCHUNK) ? csum[t] : 0u;
  d[t] = v; __syncthreads();
  for (int off = 1; off < 256; off <<= 1) {
    unsigned x = (t >= off) ? d[t - off] : 0u;
    __syncthreads();
    d[t] += x;
    __syncthreads();
  }
  if (t < NCHUNK) csum[t] = d[t] - v;   // exclusive
}

// scan3: per-bin midrank -> tTab16[b] = fp16(-log(prob(midrank)))
__global__ __launch_bounds__(256) void scan3_kernel(const unsigned* __restrict__ hist,
                                                    const unsigned* __restrict__ csum,
                                                    _Float16* __restrict__ tTab16) {
  __shared__ unsigned ts[256];
  int c = blockIdx.x, t = threadIdx.x;
  const unsigned* p = hist + (size_t)c * 512 + t * 2;
  unsigned l0 = p[0], l1 = p[1];
  unsigned s = l0 + l1;
  ts[t] = s; __syncthreads();
  for (int off = 1; off < 256; off <<= 1) {
    unsigned x = (t >= off) ? ts[t - off] : 0u;
    __syncthreads();
    ts[t] += x;
    __syncthreads();
  }
  unsigned base = csum[c] + ts[t] - s;
  int idx = c * 512 + t * 2;
  float r0 = (float)base + 0.5f * ((float)l0 - 1.0f);
  tTab16[idx]     = (_Float16)(-__logf(fmaf(r0, INV_NM1, INV_N)));
  float r1 = (float)(base + l0) + 0.5f * ((float)l1 - 1.0f);
  tTab16[idx + 1] = (_Float16)(-__logf(fmaf(r1, INV_NM1, INV_N)));
}

// ---------------- fused map + MFMA P.V + rowsum-normalized epilogue ----------------
// Wave owns 16 i-rows x 64 d x all 1024 j. A-frag built in-register from score
// (m=lane&15 row, k=quad*8+j), t looked up in LDS fp16 table, sign via bit XOR.
__global__ __launch_bounds__(256) void pv_mfma_kernel(
    const float* __restrict__ score, const _Float16* __restrict__ Vt,
    const unsigned short* __restrict__ tTab16, float* __restrict__ out) {
  __shared__ unsigned short ldsT[NHOT];
  int tid = threadIdx.x;
  {
    const unsigned* gsrc = (const unsigned*)(tTab16 + HOT_LO);
    unsigned* ldst = (unsigned*)ldsT;
    #pragma unroll
    for (int i = 0; i < 28; ++i)       // 14336/2 = 7168 = 28*256
      ldst[i * 256 + tid] = gsrc[i * 256 + tid];
  }
  __syncthreads();

  int bh   = blockIdx.y;
  int wave = tid >> 6;
  int lane = tid & 63;
  int m    = lane & 15;     // A row / B col within 16-tile
  int quad = lane >> 4;     // K sub-chunk
  int i0   = blockIdx.x * 64 + wave * 16;
  const float*    Sb = score + ((size_t)bh * S_LEN + i0 + m) * S_LEN;
  const _Float16* Vb = Vt + (size_t)bh * D_DIM * S_LEN;
  floatx4 acc[4];
  #pragma unroll
  for (int n = 0; n < 4; ++n) acc[n] = (floatx4){0.f, 0.f, 0.f, 0.f};
  float rsum = 0.f;

  for (int ks = 0; ks < 32; ++ks) {
    int k0 = ks * 32 + quad * 8;
    float4 s0 = *(const float4*)(Sb + k0);
    float4 s1 = *(const float4*)(Sb + k0 + 4);
    float sv[8] = {s0.x, s0.y, s0.z, s0.w, s1.x, s1.y, s1.z, s1.w};
    union { unsigned short u[8]; half8 h; } af;
    #pragma unroll
    for (int e = 0; e < 8; ++e) {
      unsigned u = __float_as_uint(sv[e]);
      unsigned a = u & 0x7fffffffu;
      unsigned b = a >> KSHIFT;
      if (b > NBINS - 1u) b = NBINS - 1u;
      unsigned short tb;
      if (b >= HOT_LO) tb = ldsT[b - HOT_LO];
      else             tb = tTab16[b];             // rare cold bins
      if (a == 0u) tb = 0;
      af.u[e] = (unsigned short)(tb ^ ((u >> 16) & 0x8000u));
      unsigned short tabs = (unsigned short)(tb & 0x7fffu);
      _Float16 th = __builtin_bit_cast(_Float16, tabs);
      rsum += (float)th;
    }
    half8 bf[4];
    #pragma unroll
    for (int n = 0; n < 4; ++n)
      bf[n] = *(const half8*)(Vb + (size_t)(n * 16 + m) * S_LEN + k0);
    #pragma unroll
    for (int n = 0; n < 4; ++n)
      acc[n] = __builtin_amdgcn_mfma_f32_16x16x32_f16(af.h, bf[n], acc[n], 0, 0, 0);
  }

  // rowsum: quads hold disjoint K-slices of row m -> xor-reduce across quads
  rsum += __shfl_xor(rsum, 16);
  rsum += __shfl_xor(rsum, 32);
  float inv = 1.0f / rsum;              // lane L holds inv for row L&15
  #pragma unroll
  for (int r = 0; r < 4; ++r) {
    int row = quad * 4 + r;             // C/D: row = quad*4+reg, col = lane&15
    float invr = __shfl(inv, row);
    float* op = out + ((size_t)bh * S_LEN + i0 + row) * D_DIM + m;
    #pragma unroll
    for (int n = 0; n < 4; ++n)
      op[n * 16] = acc[n][r] * invr;
  }
}

// ---------------- launch ----------------
extern "C" void kernel_launch(void* const* d_in, const int* in_sizes, int n_in,
                              void* d_out, int out_size, void* d_ws, size_t ws_size,
                              hipStream_t stream) {
  const float* Q = (const float*)d_in[0];
  const float* K = (const float*)d_in[1];
  const float* V = (const float*)d_in[2];
  float* out = (float*)d_out;
  char* ws = (char*)d_ws;
  // Layout (max 142,077,952 B == round-4-proven footprint):
  //   score   [0, 134217728)
  //   hist    [134217728, 134737920)               130048 u32
  //   P = 134737920: partial (256*14336 u16 = 7340032 B), live hist->hreduce
  //   aliased into P's range with disjoint lifetimes:
  //     csum   P+0        (1016 B,  live scan1->scan3)
  //     tTab16 P+1024     (260096 B, live scan3->pv)
  //     Vt     P+262144   (4194304 B, written by vt after hreduce, live ->pv)
  //     qinv   P+4456448, kinv P+4718592 (262144 B each, live norms->qk only)
  float*          score   = (float*)(ws);
  unsigned*       hist    = (unsigned*)(ws + 134217728);
  unsigned short* partial = (unsigned short*)(ws + 134737920);
  unsigned*       csum    = (unsigned*)(ws + 134737920);
  _Float16*       tTab16  = (_Float16*)(ws + 134738944);
  _Float16*       Vt      = (_Float16*)(ws + 135000064);
  double*         qinv    = (double*)(ws + 139194368);
  double*         kinv    = (double*)(ws + 139456512);

  hipMemsetAsync(hist, 0, NBINS * sizeof(unsigned), stream);
  norms_kernel<<<(2 * BH * S_LEN) / 4, 256, 0, stream>>>(Q, K, qinv, kinv);
  qk_kernel<<<dim3(16, 16, BH), 256, 0, stream>>>(Q, K, qinv, kinv, score);
  hist_kernel<<<HBLK, 512, 0, stream>>>(score, hist, partial);
  hreduce_kernel<<<NHOT / 256, 256, 0, stream>>>(partial, hist);
  vt_kernel<<<dim3(16, BH), 256, 0, stream>>>(V, Vt);
  scan1_kernel<<<NCHUNK, 256, 0, stream>>>(hist, csum);
  scan2_kernel<<<1, 256, 0, stream>>>(csum);
  scan3_kernel<<<NCHUNK, 256, 0, stream>>>(hist, csum, tTab16);
  pv_mfma_kernel<<<dim3(16, BH), 256, 0, stream>>>(
      score, Vt, (const unsigned short*)tTab16, out);
}